// Round 13
// baseline (1005.052 us; speedup 1.0000x reference)
//
#include <hip/hip_runtime.h>

static constexpr int KN  = 256;   // codebook entries
static constexpr int DD  = 384;   // feature dim
static constexpr int DD4 = 96;    // DD/4
static constexpr int TM  = 64;    // rows per block (64x256 block tile)
#define FLAG_MARGIN 0.005f

typedef __attribute__((ext_vector_type(8)))  short bf16x8;   // 8 bf16 = 4 VGPR
typedef __attribute__((ext_vector_type(16))) float f32x16;   // MFMA 32x32 acc

__device__ __forceinline__ unsigned short f2bf_rne(float x) {
  unsigned u = __float_as_uint(x);
  return (unsigned short)((u + 0x7fffu + ((u >> 16) & 1u)) >> 16);
}

// async global->LDS, 16B per lane (dest = wave-uniform base + lane*16)
__device__ __forceinline__ void g2lds16(const void* g, void* l) {
  __builtin_amdgcn_global_load_lds(
      (const __attribute__((address_space(1))) unsigned int*)g,
      (__attribute__((address_space(3))) unsigned int*)l, 16, 0, 0);
}

// fp32x8 (two float4) -> bf16 high/low split + xx accumulation
__device__ __forceinline__ void cvt8(float4 a, float4 b, bf16x8& h, bf16x8& l,
                                     float& xx) {
  float v[8] = {a.x, a.y, a.z, a.w, b.x, b.y, b.z, b.w};
#pragma unroll
  for (int i = 0; i < 8; ++i) {
    xx += v[i] * v[i];
    unsigned short hh = f2bf_rne(v[i]);
    float hf = __uint_as_float((unsigned)hh << 16);
    h[i] = (short)hh;
    l[i] = (short)f2bf_rne(v[i] - hf);
  }
}

// ======== numpy-fp32 emulation helpers (VALIDATED round 4 — do not touch) ====
__device__ __forceinline__ float emu_sq_pairwise384(const float* __restrict__ p) {
  float S[4];
#pragma unroll
  for (int blk = 0; blk < 4; ++blk) {
    const float* b = p + blk * 96;
    float r[8];
#pragma unroll
    for (int l = 0; l < 8; ++l) r[l] = __fmul_rn(b[l], b[l]);
    for (int j = 8; j < 96; j += 8) {
#pragma unroll
      for (int l = 0; l < 8; ++l) r[l] = __fadd_rn(r[l], __fmul_rn(b[j + l], b[j + l]));
    }
    float t1 = __fadd_rn(__fadd_rn(r[0], r[1]), __fadd_rn(r[2], r[3]));
    float t2 = __fadd_rn(__fadd_rn(r[4], r[5]), __fadd_rn(r[6], r[7]));
    S[blk] = __fadd_rn(t1, t2);
  }
  return __fadd_rn(__fadd_rn(S[0], S[1]), __fadd_rn(S[2], S[3]));
}

__device__ __forceinline__ float emu_dot384_np(const float* __restrict__ x,
                                               const float* __restrict__ c) {
  float s[16];
#pragma unroll
  for (int t = 0; t < 16; ++t) s[t] = 0.f;
  for (int j = 0; j < 384; j += 16) {
#pragma unroll
    for (int t = 0; t < 16; ++t)
      s[t] = __fadd_rn(__fmul_rn(x[j + t], c[j + t]), s[t]);
  }
  float w0 = __fadd_rn(__fadd_rn(s[0], s[4]), __fadd_rn(s[8],  s[12]));
  float w1 = __fadd_rn(__fadd_rn(s[1], s[5]), __fadd_rn(s[9],  s[13]));
  float w2 = __fadd_rn(__fadd_rn(s[2], s[6]), __fadd_rn(s[10], s[14]));
  float w3 = __fadd_rn(__fadd_rn(s[3], s[7]), __fadd_rn(s[11], s[15]));
  return __fadd_rn(__fadd_rn(w0, w1), __fadd_rn(w2, w3));
}

// ---------------- prep: codebook norms (3 blocks) + bf16-split (144 blocks) --
__global__ __launch_bounds__(256) void prep_kernel(const float* __restrict__ c0,
                                                   const float* __restrict__ c1,
                                                   const float* __restrict__ c2,
                                                   float* __restrict__ e2,
                                                   double* __restrict__ delta,
                                                   short* __restrict__ fragbase) {
  int bid = blockIdx.x;
  if (bid < 3) {
    const float* cb = (bid == 0) ? c0 : ((bid == 1) ? c1 : c2);
    e2[bid * KN + threadIdx.x] = emu_sq_pairwise384(cb + (size_t)threadIdx.x * DD);
    if (threadIdx.x == 0) delta[bid] = 0.0;
    return;
  }
  int sb = bid - 3;                 // 0..143
  int lvl = sb / 48;
  int blk48 = sb - lvl * 48;
  const float* cb = (lvl == 0) ? c0 : ((lvl == 1) ? c1 : c2);
  short* frag = fragbase + (size_t)lvl * 196608;
  int gid = blk48 * 256 + threadIdx.x;            // 12288 = 256 entries * 48 groups
  int e = gid / 48;
  int g = gid - e * 48;
  const float4* s4 = reinterpret_cast<const float4*>(cb) + (size_t)e * 96 + g * 2;
  float4 v0 = s4[0], v1 = s4[1];
  float xs[8] = {v0.x, v0.y, v0.z, v0.w, v1.x, v1.y, v1.z, v1.w};
  short h[8], l[8];
#pragma unroll
  for (int i = 0; i < 8; ++i) {
    h[i] = (short)f2bf_rne(xs[i]);
    float hf = __uint_as_float((unsigned)(unsigned short)h[i] << 16);
    l[i] = (short)f2bf_rne(xs[i] - hf);
  }
  int c = g >> 2, rem = g & 3, ks = rem >> 1, hs = rem & 1;
  int t = e >> 5, lane = (e & 31) + (hs << 5);
  size_t blk = (((size_t)(c * 8 + t) * 2 + ks) * 2);
  short* dh = frag + blk * 512 + lane * 8;
  short* dl = dh + 512;
  *reinterpret_cast<bf16x8*>(dh) = *reinterpret_cast<const bf16x8*>(h);
  *reinterpret_cast<bf16x8*>(dl) = *reinterpret_cast<const bf16x8*>(l);
}

// ---------------- phase 1: merged 3-level MFMA GEMM, 2-phase pipelined ------
// 4 waves in 2x2: wave (wr,wc) owns rows wr*32..+31, cols wc*128..+127.
// X A-fragments: global->register direct (lane l = row lr, k = c*32+ks*16+hi*8+j),
// prefetched one chunk ahead. CB: double-buffered LDS via global_load_lds,
// issued one chunk ahead; the end-of-iteration __syncthreads' implicit
// vmcnt(0) drain is hidden under the MFMA phase (T3 minimum 2-phase).
__global__ __launch_bounds__(256) void vq_main(
    const float* __restrict__ X0, const float* __restrict__ X1, const float* __restrict__ X2,
    const float* __restrict__ C0, const float* __restrict__ C1, const float* __restrict__ C2,
    const short* __restrict__ FRAGBASE,
    const float* __restrict__ E2A,
    float* __restrict__ QBASE,
    float* __restrict__ IDXBASE,
    unsigned char* __restrict__ FLAGBASE,
    double* __restrict__ PART,
    int nb0, int nb1)
{
  __shared__ __align__(16) short cb_lds[2][16384];  // 2 x 32KB double buffer
  __shared__ int idx_s[TM];
  __shared__ float xx_s[TM];
  __shared__ float cand_b1[2][TM];
  __shared__ int   cand_i1[2][TM];
  __shared__ float cand_b2[2][TM];

  const int bid = blockIdx.x;
  int lvl, lb;
  if (bid < nb0)            { lvl = 0; lb = bid; }
  else if (bid < nb0 + nb1) { lvl = 1; lb = bid - nb0; }
  else                      { lvl = 2; lb = bid - nb0 - nb1; }
  const float* X  = (lvl == 0) ? X0 : ((lvl == 1) ? X1 : X2);
  const float* CBF32 = (lvl == 0) ? C0 : ((lvl == 1) ? C1 : C2);
  const short* CBFRAG = FRAGBASE + (size_t)lvl * 196608;
  const float* E2 = E2A + lvl * KN;
  const size_t rowbase = (lvl == 0) ? 0 : ((lvl == 1) ? (size_t)nb0 * TM
                                                      : (size_t)(nb0 + nb1) * TM);
  float* Q = QBASE + rowbase * DD;
  float* IDXO = IDXBASE + rowbase;
  unsigned char* FLAG = FLAGBASE + rowbase;
  const size_t row0 = (size_t)lb * TM;

  const int tid  = threadIdx.x;
  const int wid  = tid >> 6, lane = tid & 63;
  const int lr   = lane & 31, hi = lane >> 5;
  const int wr   = wid >> 1, wc = wid & 1;

  const float4* X4 = reinterpret_cast<const float4*>(X);
  // this lane's X row pointer (A-fragment source): row = row0+wr*32+lr
  const float4* xrow = X4 + (row0 + (size_t)(wr * 32 + lr)) * DD4 + hi * 2;

  f32x16 acc[4];
  {
    f32x16 z;
#pragma unroll
    for (int i = 0; i < 16; ++i) z[i] = 0.f;
#pragma unroll
    for (int ct = 0; ct < 4; ++ct) acc[ct] = z;
  }
  float xx = 0.f;

  // ---- prologue: prefetch chunk 0 (X -> regs, CB -> buf0) ----
  float4 xr0 = xrow[0], xr1 = xrow[1], xr2 = xrow[4], xr3 = xrow[5];
  {
    const char* gsrc = (const char*)CBFRAG + (size_t)tid * 16;
#pragma unroll
    for (int s = 0; s < 8; ++s)
      g2lds16(gsrc + s * 4096, (char*)cb_lds[0] + tid * 16 + s * 4096);
  }
  __syncthreads();   // drain prologue loads (one exposed drain only)

#pragma unroll 1
  for (int c = 0; c < 12; ++c) {
    // convert prefetched X (data already resident)
    bf16x8 ah0, al0, ah1, al1;
    cvt8(xr0, xr1, ah0, al0, xx);   // ks=0 fragment
    cvt8(xr2, xr3, ah1, al1, xx);   // ks=1 fragment

    if (c < 11) {
      // prefetch chunk c+1: X -> regs (WAR on xr* is in-register, safe)
      const float4* xp = xrow + (c + 1) * 8;
      xr0 = xp[0]; xr1 = xp[1]; xr2 = xp[4]; xr3 = xp[5];
      // prefetch chunk c+1: CB -> other LDS buffer
      const char* gsrc = (const char*)CBFRAG + (size_t)(c + 1) * 32768 + tid * 16;
      char* dst = (char*)cb_lds[(c + 1) & 1] + tid * 16;
#pragma unroll
      for (int s = 0; s < 8; ++s)
        g2lds16(gsrc + s * 4096, dst + s * 4096);
    }

    // MFMA phase on current buffer (hides the prefetch latency)
    const bf16x8* bb = reinterpret_cast<const bf16x8*>(cb_lds[c & 1]);
#pragma unroll
    for (int ct = 0; ct < 4; ++ct) {
      int t = wc * 4 + ct;
      bf16x8 bh0 = bb[((t * 2 + 0) * 2 + 0) * 64 + lane];
      bf16x8 bl0 = bb[((t * 2 + 0) * 2 + 1) * 64 + lane];
      bf16x8 bh1 = bb[((t * 2 + 1) * 2 + 0) * 64 + lane];
      bf16x8 bl1 = bb[((t * 2 + 1) * 2 + 1) * 64 + lane];
      acc[ct] = __builtin_amdgcn_mfma_f32_32x32x16_bf16(ah0, bh0, acc[ct], 0, 0, 0);
      acc[ct] = __builtin_amdgcn_mfma_f32_32x32x16_bf16(ah0, bl0, acc[ct], 0, 0, 0);
      acc[ct] = __builtin_amdgcn_mfma_f32_32x32x16_bf16(al0, bh0, acc[ct], 0, 0, 0);
      acc[ct] = __builtin_amdgcn_mfma_f32_32x32x16_bf16(ah1, bh1, acc[ct], 0, 0, 0);
      acc[ct] = __builtin_amdgcn_mfma_f32_32x32x16_bf16(ah1, bl1, acc[ct], 0, 0, 0);
      acc[ct] = __builtin_amdgcn_mfma_f32_32x32x16_bf16(al1, bh1, acc[ct], 0, 0, 0);
    }
    if (c != 11) __syncthreads();  // vmcnt drain hidden under the MFMA phase
  }

  // ---- row norms: lane + partner(lane^32) cover the full row ----
  xx += __shfl_xor(xx, 32);
  if (wc == 0 && hi == 0) xx_s[wr * 32 + lr] = xx;

  // ---- argmin epilogue: D layout col=lane&31, row=(v&3)+8*(v>>2)+4*hi ----
  float e2v[4];
#pragma unroll
  for (int ct = 0; ct < 4; ++ct) e2v[ct] = E2[wc * 128 + ct * 32 + lr];

#pragma unroll
  for (int v = 0; v < 16; ++v) {
    int rloc = (v & 3) + 8 * (v >> 2) + 4 * hi;
    int row = wr * 32 + rloc;
    float b1 = 1e30f; int i1 = 0x7fffffff;
#pragma unroll
    for (int ct = 0; ct < 4; ++ct) {
      float sc = e2v[ct] - 2.0f * acc[ct][v];
      int col = wc * 128 + ct * 32 + lr;
      if (sc < b1) { b1 = sc; i1 = col; }
    }
#pragma unroll
    for (int m = 1; m < 32; m <<= 1) {     // within 32-lane halves (hi preserved)
      float ob = __shfl_xor(b1, m);
      int   oi = __shfl_xor(i1, m);
      if (ob < b1 || (ob == b1 && oi < i1)) { b1 = ob; i1 = oi; }
    }
    float b2 = 1e30f;
#pragma unroll
    for (int ct = 0; ct < 4; ++ct) {
      float sc = e2v[ct] - 2.0f * acc[ct][v];
      int col = wc * 128 + ct * 32 + lr;
      if (col != i1 && sc < b2) b2 = sc;
    }
#pragma unroll
    for (int m = 1; m < 32; m <<= 1) {
      float ob = __shfl_xor(b2, m);
      if (ob < b2) b2 = ob;
    }
    if (lr == 0) {
      cand_b1[wc][row] = b1; cand_i1[wc][row] = i1; cand_b2[wc][row] = b2;
    }
  }
  __syncthreads();

  // merge col-halves; idx/flag; per-row loss = xx + b1
  double lrow = 0.0;
  if (tid < TM) {
    float a1 = cand_b1[0][tid], a2 = cand_b2[0][tid];
    int   ai = cand_i1[0][tid];
    float c1 = cand_b1[1][tid], c2 = cand_b2[1][tid];
    int   ci = cand_i1[1][tid];
    float b1; int i1; float b2;
    if (c1 < a1 || (c1 == a1 && ci < ai)) {
      b1 = c1; i1 = ci; b2 = (a1 < c2) ? a1 : c2;
    } else {
      b1 = a1; i1 = ai; b2 = (c1 < a2) ? c1 : a2;
    }
    idx_s[tid] = i1;
    IDXO[row0 + tid] = (float)i1;
    FLAG[row0 + tid] = (b2 - b1 < FLAG_MARGIN) ? 1 : 0;
    lrow = (double)xx_s[tid] + (double)b1;
  }
  if (tid < 64) {
#pragma unroll
    for (int m = 1; m < 64; m <<= 1) lrow += __shfl_xor(lrow, m);
    if (tid == 0) PART[bid] = lrow;
  }
  __syncthreads();

  // ---- output: q = cb[idx] (pure gather+write; no X re-read) ----
  const float4* CB4 = reinterpret_cast<const float4*>(CBF32);
  float4* Q4 = reinterpret_cast<float4*>(Q);
  for (int i = tid; i < TM * DD4; i += 256) {
    int r = i / DD4;
    int cc = i - r * DD4;
    Q4[(row0 + (size_t)r) * DD4 + cc] = CB4[(size_t)idx_s[r] * DD4 + cc];
  }
}

// ---------------- phase 2: numpy-exact refine, all 3 levels, one launch -----
__global__ __launch_bounds__(256) void vq_refine(
    const float* __restrict__ X0, const float* __restrict__ X1, const float* __restrict__ X2,
    const float* __restrict__ C0, const float* __restrict__ C1, const float* __restrict__ C2,
    const float* __restrict__ E2A,
    const unsigned char* __restrict__ F0, const unsigned char* __restrict__ F1,
    const unsigned char* __restrict__ F2,
    int r0, int r1, int r2,
    float* __restrict__ Q0, float* __restrict__ Q1, float* __restrict__ Q2,
    float* __restrict__ I0, float* __restrict__ I1, float* __restrict__ I2,
    double* __restrict__ DELTA)
{
  const int lane   = threadIdx.x & 63;
  const int gwave  = (blockIdx.x * blockDim.x + threadIdx.x) >> 6;
  const int nwaves = (gridDim.x * blockDim.x) >> 6;
  const int ntot = r0 + r1 + r2;

  for (int base = gwave * 64; base < ntot; base += nwaves * 64) {
    int lvl, lb;
    const float *X, *CB; const unsigned char* FLAG; float *Q, *IDXO;
    if (base < r0)           { lvl = 0; lb = base;            X = X0; CB = C0; FLAG = F0; Q = Q0; IDXO = I0; }
    else if (base < r0 + r1) { lvl = 1; lb = base - r0;       X = X1; CB = C1; FLAG = F1; Q = Q1; IDXO = I1; }
    else                     { lvl = 2; lb = base - r0 - r1;  X = X2; CB = C2; FLAG = F2; Q = Q2; IDXO = I2; }
    const float* E2EMU = E2A + lvl * KN;

    unsigned char f = FLAG[lb + lane];
    unsigned long long mask = __ballot(f != 0);
    while (mask) {
      int bit = __ffsll((long long)mask) - 1;
      mask &= mask - 1;
      const int r = lb + bit;
      const float* xr = X + (size_t)r * DD;
      const float xx = emu_sq_pairwise384(xr);

      float best = 1e30f; int bidx = 0x7fffffff;
#pragma unroll
      for (int t = 0; t < 4; ++t) {
        int k = lane * 4 + t;
        const float* ck = CB + (size_t)k * DD;
        float E = emu_dot384_np(xr, ck);
        float s = __fadd_rn(__fsub_rn(xx, __fmul_rn(2.0f, E)), E2EMU[k]);
        if (s < best || (s == best && k < bidx)) { best = s; bidx = k; }
      }
#pragma unroll
      for (int m = 1; m < 64; m <<= 1) {
        float ob = __shfl_xor(best, m);
        int   oi = __shfl_xor(bidx, m);
        if (ob < best || (ob == best && oi < bidx)) { best = ob; bidx = oi; }
      }

      const int old = (int)IDXO[r];
      if (bidx != old) {
        const float* cn = CB + (size_t)bidx * DD;
        const float* co = CB + (size_t)old * DD;
        double dl = 0.0;
        for (int d = lane; d < DD; d += 64) {
          float xv = xr[d];
          float qn = cn[d], qo = co[d];
          Q[(size_t)r * DD + d] = qn;
          double en = (double)qn - (double)xv;
          double eo = (double)qo - (double)xv;
          dl += en * en - eo * eo;
        }
#pragma unroll
        for (int m = 1; m < 64; m <<= 1) dl += __shfl_xor(dl, m);
        if (lane == 0) {
          atomicAdd(DELTA + lvl, dl);
          IDXO[r] = (float)bidx;
        }
      }
    }
  }
}

// ---------------- loss finalize ----------------
__global__ void finalize_kernel(const double* __restrict__ p0, int n0, double w0,
                                const double* __restrict__ p1, int n1, double w1,
                                const double* __restrict__ p2, int n2, double w2,
                                const double* __restrict__ delta,
                                float* __restrict__ out) {
  __shared__ double red[4];
  int tid = threadIdx.x;
  double s0 = 0.0, s1 = 0.0, s2 = 0.0;
  for (int i = tid; i < n0; i += 256) s0 += p0[i];
  for (int i = tid; i < n1; i += 256) s1 += p1[i];
  for (int i = tid; i < n2; i += 256) s2 += p2[i];
  double v = s0 * w0 + s1 * w1 + s2 * w2;
#pragma unroll
  for (int m = 1; m < 64; m <<= 1) v += __shfl_xor(v, m);
  if ((tid & 63) == 0) red[tid >> 6] = v;
  __syncthreads();
  if (tid == 0)
    out[0] = (float)(red[0] + red[1] + red[2] + red[3]
                     + delta[0] * w0 + delta[1] * w1 + delta[2] * w2);
}

extern "C" void kernel_launch(void* const* d_in, const int* in_sizes, int n_in,
                              void* d_out, int out_size, void* d_ws, size_t ws_size,
                              hipStream_t stream) {
  const float* l0  = (const float*)d_in[0];
  const float* l1  = (const float*)d_in[1];
  const float* l2  = (const float*)d_in[2];
  const float* cb0 = (const float*)d_in[3];
  const float* cb1 = (const float*)d_in[4];
  const float* cb2 = (const float*)d_in[5];

  const size_t n_q0 = (size_t)in_sizes[0];
  const size_t n_q1 = (size_t)in_sizes[1];
  const size_t n_q2 = (size_t)in_sizes[2];
  const int r0 = (int)(n_q0 / DD);   // 65536
  const int r1 = (int)(n_q1 / DD);   // 262144
  const int r2 = (int)(n_q2 / DD);   // 262144

  float* out   = (float*)d_out;
  float* q0    = out;
  float* q1    = q0 + n_q0;
  float* q2    = q1 + n_q1;
  float* lossp = q2 + n_q2;
  float* idx0  = lossp + 1;
  float* idx1  = idx0 + r0;
  float* idx2  = idx1 + r1;

  // ws layout
  float*  e2    = (float*)d_ws;                          // 3*256 f32
  double* part  = (double*)((char*)d_ws + 4096);         // 9216 doubles
  double* delta = (double*)((char*)d_ws + 4096 + 73728);
  unsigned char* flag0 = (unsigned char*)d_ws + 4096 + 73728 + 1024;
  unsigned char* flag1 = flag0 + r0;
  unsigned char* flag2 = flag1 + r1;
  short* cbf0 = (short*)((char*)d_ws + (1 << 20));       // 3 x 384 KiB

  const int nb0 = r0 / TM, nb1 = r1 / TM, nb2 = r2 / TM;  // 1024/4096/4096
  double* p0 = part;
  double* p1 = p0 + nb0;
  double* p2 = p1 + nb1;

  prep_kernel<<<147, 256, 0, stream>>>(cb0, cb1, cb2, e2, delta, cbf0);

  vq_main<<<nb0 + nb1 + nb2, 256, 0, stream>>>(
      l0, l1, l2, cb0, cb1, cb2, cbf0, e2,
      q0, idx0, flag0, part, nb0, nb1);

  vq_refine<<<512, 256, 0, stream>>>(l0, l1, l2, cb0, cb1, cb2, e2,
                                     flag0, flag1, flag2, r0, r1, r2,
                                     q0, q1, q2, idx0, idx1, idx2, delta);

  const double w0 = 0.05 / ((double)r0 * DD);
  const double w1 = 0.25 / ((double)r1 * DD);
  const double w2 = 0.60 / ((double)r2 * DD);
  finalize_kernel<<<1, 256, 0, stream>>>(p0, nb0, w0, p1, nb1, w1, p2, nb2, w2,
                                         delta, lossp);
}

// Round 14
// 881.212 us; speedup vs baseline: 1.1405x; 1.1405x over previous
//
#include <hip/hip_runtime.h>

static constexpr int KN  = 256;   // codebook entries
static constexpr int DD  = 384;   // feature dim
static constexpr int DD4 = 96;    // DD/4
static constexpr int TM  = 64;    // rows per block (64x256 block tile)
#define FLAG_MARGIN 0.005f

typedef __attribute__((ext_vector_type(8)))  short bf16x8;   // 8 bf16 = 4 VGPR
typedef __attribute__((ext_vector_type(16))) float f32x16;   // MFMA 32x32 acc
typedef __attribute__((ext_vector_type(4)))  short short4v;

__device__ __forceinline__ unsigned short f2bf_rne(float x) {
  unsigned u = __float_as_uint(x);
  return (unsigned short)((u + 0x7fffu + ((u >> 16) & 1u)) >> 16);
}

// async global->LDS, 16B per lane (dest = wave-uniform base + lane*16)
__device__ __forceinline__ void g2lds16(const void* g, void* l) {
  __builtin_amdgcn_global_load_lds(
      (const __attribute__((address_space(1))) unsigned int*)g,
      (__attribute__((address_space(3))) unsigned int*)l, 16, 0, 0);
}

// ======== numpy-fp32 emulation helpers (VALIDATED round 4 — do not touch) ====
__device__ __forceinline__ float emu_sq_pairwise384(const float* __restrict__ p) {
  float S[4];
#pragma unroll
  for (int blk = 0; blk < 4; ++blk) {
    const float* b = p + blk * 96;
    float r[8];
#pragma unroll
    for (int l = 0; l < 8; ++l) r[l] = __fmul_rn(b[l], b[l]);
    for (int j = 8; j < 96; j += 8) {
#pragma unroll
      for (int l = 0; l < 8; ++l) r[l] = __fadd_rn(r[l], __fmul_rn(b[j + l], b[j + l]));
    }
    float t1 = __fadd_rn(__fadd_rn(r[0], r[1]), __fadd_rn(r[2], r[3]));
    float t2 = __fadd_rn(__fadd_rn(r[4], r[5]), __fadd_rn(r[6], r[7]));
    S[blk] = __fadd_rn(t1, t2);
  }
  return __fadd_rn(__fadd_rn(S[0], S[1]), __fadd_rn(S[2], S[3]));
}

__device__ __forceinline__ float emu_dot384_np(const float* __restrict__ x,
                                               const float* __restrict__ c) {
  float s[16];
#pragma unroll
  for (int t = 0; t < 16; ++t) s[t] = 0.f;
  for (int j = 0; j < 384; j += 16) {
#pragma unroll
    for (int t = 0; t < 16; ++t)
      s[t] = __fadd_rn(__fmul_rn(x[j + t], c[j + t]), s[t]);
  }
  float w0 = __fadd_rn(__fadd_rn(s[0], s[4]), __fadd_rn(s[8],  s[12]));
  float w1 = __fadd_rn(__fadd_rn(s[1], s[5]), __fadd_rn(s[9],  s[13]));
  float w2 = __fadd_rn(__fadd_rn(s[2], s[6]), __fadd_rn(s[10], s[14]));
  float w3 = __fadd_rn(__fadd_rn(s[3], s[7]), __fadd_rn(s[11], s[15]));
  return __fadd_rn(__fadd_rn(w0, w1), __fadd_rn(w2, w3));
}

// ---------------- prep: codebook norms (3 blocks) + bf16-split (144 blocks) --
__global__ __launch_bounds__(256) void prep_kernel(const float* __restrict__ c0,
                                                   const float* __restrict__ c1,
                                                   const float* __restrict__ c2,
                                                   float* __restrict__ e2,
                                                   double* __restrict__ delta,
                                                   short* __restrict__ fragbase) {
  int bid = blockIdx.x;
  if (bid < 3) {
    const float* cb = (bid == 0) ? c0 : ((bid == 1) ? c1 : c2);
    e2[bid * KN + threadIdx.x] = emu_sq_pairwise384(cb + (size_t)threadIdx.x * DD);
    if (threadIdx.x == 0) delta[bid] = 0.0;
    return;
  }
  int sb = bid - 3;                 // 0..143
  int lvl = sb / 48;
  int blk48 = sb - lvl * 48;
  const float* cb = (lvl == 0) ? c0 : ((lvl == 1) ? c1 : c2);
  short* frag = fragbase + (size_t)lvl * 196608;
  int gid = blk48 * 256 + threadIdx.x;            // 12288 = 256 entries * 48 groups
  int e = gid / 48;
  int g = gid - e * 48;
  const float4* s4 = reinterpret_cast<const float4*>(cb) + (size_t)e * 96 + g * 2;
  float4 v0 = s4[0], v1 = s4[1];
  float xs[8] = {v0.x, v0.y, v0.z, v0.w, v1.x, v1.y, v1.z, v1.w};
  short h[8], l[8];
#pragma unroll
  for (int i = 0; i < 8; ++i) {
    h[i] = (short)f2bf_rne(xs[i]);
    float hf = __uint_as_float((unsigned)(unsigned short)h[i] << 16);
    l[i] = (short)f2bf_rne(xs[i] - hf);
  }
  int c = g >> 2, rem = g & 3, ks = rem >> 1, hs = rem & 1;
  int t = e >> 5, lane = (e & 31) + (hs << 5);
  size_t blk = (((size_t)(c * 8 + t) * 2 + ks) * 2);
  short* dh = frag + blk * 512 + lane * 8;
  short* dl = dh + 512;
  *reinterpret_cast<bf16x8*>(dh) = *reinterpret_cast<const bf16x8*>(h);
  *reinterpret_cast<bf16x8*>(dl) = *reinterpret_cast<const bf16x8*>(l);
}

// ---------------- phase 1: merged 3-level MFMA GEMM, 16k-chunk 2-phase ------
// 4 waves, wave wid owns ALL 64 rows x cols [wid*64, wid*64+64) as 2 row-tiles
// x 2 col-tiles of 32x32 -> acc[4] = 64 AGPR. Chunk = 16 k. CB and X both
// double-buffered in LDS (fragment-ordered, lane-linear 16B -> conflict-free
// b128 reads). X converted once per element (256 threads cover 64x16 chunk).
__global__ __launch_bounds__(256) void vq_main(
    const float* __restrict__ X0, const float* __restrict__ X1, const float* __restrict__ X2,
    const float* __restrict__ C0, const float* __restrict__ C1, const float* __restrict__ C2,
    const short* __restrict__ FRAGBASE,
    const float* __restrict__ E2A,
    float* __restrict__ QBASE,
    float* __restrict__ IDXBASE,
    unsigned char* __restrict__ FLAGBASE,
    double* __restrict__ PART,
    int nb0, int nb1)
{
  __shared__ __align__(16) short cb_lds[2][8192];   // 2 x 16KB: [t(8)][hl(2)] 1KB
  __shared__ __align__(16) short x_lds[2][2048];    // 2 x 4KB:  [rt(2)][hl(2)] 1KB
  __shared__ int idx_s[TM];
  __shared__ float xx_s[TM];
  __shared__ float cand_b1[4][TM];
  __shared__ int   cand_i1[4][TM];
  __shared__ float cand_b2[4][TM];

  const int bid = blockIdx.x;
  int lvl, lb;
  if (bid < nb0)            { lvl = 0; lb = bid; }
  else if (bid < nb0 + nb1) { lvl = 1; lb = bid - nb0; }
  else                      { lvl = 2; lb = bid - nb0 - nb1; }
  const float* X  = (lvl == 0) ? X0 : ((lvl == 1) ? X1 : X2);
  const float* CBF32 = (lvl == 0) ? C0 : ((lvl == 1) ? C1 : C2);
  const short* CBFRAG = FRAGBASE + (size_t)lvl * 196608;
  const float* E2 = E2A + lvl * KN;
  const size_t rowbase = (lvl == 0) ? 0 : ((lvl == 1) ? (size_t)nb0 * TM
                                                      : (size_t)(nb0 + nb1) * TM);
  float* Q = QBASE + rowbase * DD;
  float* IDXO = IDXBASE + rowbase;
  unsigned char* FLAG = FLAGBASE + rowbase;
  const size_t row0 = (size_t)lb * TM;

  const int tid  = threadIdx.x;
  const int wid  = tid >> 6, lane = tid & 63;
  const int lr   = lane & 31, hi = lane >> 5;
  const int r_st = tid >> 2, f4 = tid & 3;   // staging: row, float4-slot

  const float4* X4 = reinterpret_cast<const float4*>(X);
  const float4* xsrc = X4 + (row0 + (size_t)r_st) * DD4 + f4;

  f32x16 acc[4];   // [rt*2 + cti], all indices compile-time (rule #20)
  {
    f32x16 z;
#pragma unroll
    for (int i = 0; i < 16; ++i) z[i] = 0.f;
#pragma unroll
    for (int i = 0; i < 4; ++i) acc[i] = z;
  }
  float xx = 0.f;

  // X write target within a buffer: element (r_st, k=f4*4..+3), hi_k=f4>>1
  const int xboff = (r_st >> 5) * 2048;                            // rt block pair
  const int xpos  = ((f4 >> 1) * 32 + (r_st & 31)) * 16 + (f4 & 1) * 8;

#define STAGE_CB(CN)                                                          \
  {                                                                           \
    int c2_ = (CN) >> 1, ks_ = (CN) & 1;                                      \
    _Pragma("unroll")                                                         \
    for (int s = 0; s < 4; ++s) {                                             \
      int idx = s * 256 + tid;                                                \
      int b = idx >> 6;                                                       \
      const char* src = (const char*)CBFRAG                                   \
          + (((size_t)(c2_ * 8 + (b >> 1)) * 4 + ks_ * 2 + (b & 1)) << 10)    \
          + (idx & 63) * 16;                                                  \
      g2lds16(src, (char*)cb_lds[(CN) & 1] + idx * 16);                       \
    }                                                                         \
  }

#define CVT_WRITE_X(CN, XF)                                                   \
  {                                                                           \
    float a_[4] = {(XF).x, (XF).y, (XF).z, (XF).w};                           \
    short hh_[4], ll_[4];                                                     \
    _Pragma("unroll")                                                         \
    for (int i = 0; i < 4; ++i) {                                             \
      xx = fmaf(a_[i], a_[i], xx);                                            \
      unsigned u_ = __float_as_uint(a_[i]);                                   \
      unsigned t_ = u_ + 0x7fffu + ((u_ >> 16) & 1u);                         \
      hh_[i] = (short)(t_ >> 16);                                             \
      float hf_ = __uint_as_float(t_ & 0xffff0000u);                          \
      float lf_ = a_[i] - hf_;                                                \
      ll_[i] = (short)(__float_as_uint(lf_) >> 16);                           \
    }                                                                         \
    char* xb_ = (char*)x_lds[(CN) & 1];                                       \
    *reinterpret_cast<short4v*>(xb_ + xboff + xpos) =                         \
        *reinterpret_cast<short4v*>(hh_);                                     \
    *reinterpret_cast<short4v*>(xb_ + xboff + 1024 + xpos) =                  \
        *reinterpret_cast<short4v*>(ll_);                                     \
  }

  // ---- prologue: stage chunk 0 ----
  STAGE_CB(0);
  {
    float4 xf0 = xsrc[0];
    CVT_WRITE_X(0, xf0);
  }
  __syncthreads();

#pragma unroll 1
  for (int c = 0; c < 24; ++c) {
    float4 xf;
    if (c < 23) {
      STAGE_CB(c + 1);
      xf = xsrc[(c + 1) * 4];
    }

    // MFMA phase on buffer c&1 (hides the prefetch latency)
    const char* xb = (const char*)x_lds[c & 1];
    bf16x8 ah0 = *reinterpret_cast<const bf16x8*>(xb +        lane * 16);
    bf16x8 al0 = *reinterpret_cast<const bf16x8*>(xb + 1024 + lane * 16);
    bf16x8 ah1 = *reinterpret_cast<const bf16x8*>(xb + 2048 + lane * 16);
    bf16x8 al1 = *reinterpret_cast<const bf16x8*>(xb + 3072 + lane * 16);
    const bf16x8* bb = reinterpret_cast<const bf16x8*>(cb_lds[c & 1]);
#pragma unroll
    for (int cti = 0; cti < 2; ++cti) {
      int t = wid * 2 + cti;
      bf16x8 bh = bb[(t * 2 + 0) * 64 + lane];
      bf16x8 bl = bb[(t * 2 + 1) * 64 + lane];
      acc[cti]     = __builtin_amdgcn_mfma_f32_32x32x16_bf16(ah0, bh, acc[cti], 0, 0, 0);
      acc[cti]     = __builtin_amdgcn_mfma_f32_32x32x16_bf16(ah0, bl, acc[cti], 0, 0, 0);
      acc[cti]     = __builtin_amdgcn_mfma_f32_32x32x16_bf16(al0, bh, acc[cti], 0, 0, 0);
      acc[2 + cti] = __builtin_amdgcn_mfma_f32_32x32x16_bf16(ah1, bh, acc[2 + cti], 0, 0, 0);
      acc[2 + cti] = __builtin_amdgcn_mfma_f32_32x32x16_bf16(ah1, bl, acc[2 + cti], 0, 0, 0);
      acc[2 + cti] = __builtin_amdgcn_mfma_f32_32x32x16_bf16(al1, bh, acc[2 + cti], 0, 0, 0);
    }

    if (c < 23) CVT_WRITE_X(c + 1, xf);
    if (c != 23) __syncthreads();
  }

  // ---- row norms: reduce across the 4-thread f4 group ----
  xx += __shfl_xor(xx, 1);
  xx += __shfl_xor(xx, 2);
  if (f4 == 0) xx_s[r_st] = xx;

  // ---- argmin epilogue: D layout col=lane&31, row=(v&3)+8*(v>>2)+4*hi ----
  float e2v[2];
  e2v[0] = E2[wid * 64 + lr];
  e2v[1] = E2[wid * 64 + 32 + lr];
  const int c0i = wid * 64 + lr, c1i = wid * 64 + 32 + lr;

#pragma unroll
  for (int rt = 0; rt < 2; ++rt) {
#pragma unroll
    for (int v = 0; v < 16; ++v) {
      int row = rt * 32 + (v & 3) + 8 * (v >> 2) + 4 * hi;
      float s0 = e2v[0] - 2.0f * acc[rt * 2 + 0][v];
      float s1 = e2v[1] - 2.0f * acc[rt * 2 + 1][v];
      float b1; int i1;
      if (s0 <= s1) { b1 = s0; i1 = c0i; } else { b1 = s1; i1 = c1i; }
#pragma unroll
      for (int m = 1; m < 32; m <<= 1) {   // within 32-lane halves (hi preserved)
        float ob = __shfl_xor(b1, m);
        int   oi = __shfl_xor(i1, m);
        if (ob < b1 || (ob == b1 && oi < i1)) { b1 = ob; i1 = oi; }
      }
      float b2 = 1e30f;
      if (c0i != i1 && s0 < b2) b2 = s0;
      if (c1i != i1 && s1 < b2) b2 = s1;
#pragma unroll
      for (int m = 1; m < 32; m <<= 1) {
        float ob = __shfl_xor(b2, m);
        if (ob < b2) b2 = ob;
      }
      if (lr == 0) {
        cand_b1[wid][row] = b1; cand_i1[wid][row] = i1; cand_b2[wid][row] = b2;
      }
    }
  }
  __syncthreads();

  // merge 4 waves' candidates; idx/flag; per-row loss = xx + b1
  double lrow = 0.0;
  if (tid < TM) {
    float b1 = cand_b1[0][tid]; int i1 = cand_i1[0][tid]; float b2 = cand_b2[0][tid];
#pragma unroll
    for (int w = 1; w < 4; ++w) {
      float ob1 = cand_b1[w][tid]; int oi1 = cand_i1[w][tid]; float ob2 = cand_b2[w][tid];
      if (ob1 < b1 || (ob1 == b1 && oi1 < i1)) {
        b2 = fminf(b1, ob2); b1 = ob1; i1 = oi1;
      } else {
        b2 = fminf(b2, ob1);
      }
    }
    idx_s[tid] = i1;
    IDXO[row0 + tid] = (float)i1;
    FLAG[row0 + tid] = (b2 - b1 < FLAG_MARGIN) ? 1 : 0;
    lrow = (double)xx_s[tid] + (double)b1;
  }
  if (tid < 64) {
#pragma unroll
    for (int m = 1; m < 64; m <<= 1) lrow += __shfl_xor(lrow, m);
    if (tid == 0) PART[bid] = lrow;
  }
  __syncthreads();

  // ---- output: q = cb[idx] (pure gather+write; no X re-read) ----
  const float4* CB4 = reinterpret_cast<const float4*>(CBF32);
  float4* Q4 = reinterpret_cast<float4*>(Q);
  for (int i = tid; i < TM * DD4; i += 256) {
    int r = i / DD4;
    int cc = i - r * DD4;
    Q4[(row0 + (size_t)r) * DD4 + cc] = CB4[(size_t)idx_s[r] * DD4 + cc];
  }
}

// ---------------- phase 2: numpy-exact refine, all 3 levels, one launch -----
__global__ __launch_bounds__(256) void vq_refine(
    const float* __restrict__ X0, const float* __restrict__ X1, const float* __restrict__ X2,
    const float* __restrict__ C0, const float* __restrict__ C1, const float* __restrict__ C2,
    const float* __restrict__ E2A,
    const unsigned char* __restrict__ F0, const unsigned char* __restrict__ F1,
    const unsigned char* __restrict__ F2,
    int r0, int r1, int r2,
    float* __restrict__ Q0, float* __restrict__ Q1, float* __restrict__ Q2,
    float* __restrict__ I0, float* __restrict__ I1, float* __restrict__ I2,
    double* __restrict__ DELTA)
{
  const int lane   = threadIdx.x & 63;
  const int gwave  = (blockIdx.x * blockDim.x + threadIdx.x) >> 6;
  const int nwaves = (gridDim.x * blockDim.x) >> 6;
  const int ntot = r0 + r1 + r2;

  for (int base = gwave * 64; base < ntot; base += nwaves * 64) {
    int lvl, lb;
    const float *X, *CB; const unsigned char* FLAG; float *Q, *IDXO;
    if (base < r0)           { lvl = 0; lb = base;            X = X0; CB = C0; FLAG = F0; Q = Q0; IDXO = I0; }
    else if (base < r0 + r1) { lvl = 1; lb = base - r0;       X = X1; CB = C1; FLAG = F1; Q = Q1; IDXO = I1; }
    else                     { lvl = 2; lb = base - r0 - r1;  X = X2; CB = C2; FLAG = F2; Q = Q2; IDXO = I2; }
    const float* E2EMU = E2A + lvl * KN;

    unsigned char f = FLAG[lb + lane];
    unsigned long long mask = __ballot(f != 0);
    while (mask) {
      int bit = __ffsll((long long)mask) - 1;
      mask &= mask - 1;
      const int r = lb + bit;
      const float* xr = X + (size_t)r * DD;
      const float xx = emu_sq_pairwise384(xr);

      float best = 1e30f; int bidx = 0x7fffffff;
#pragma unroll
      for (int t = 0; t < 4; ++t) {
        int k = lane * 4 + t;
        const float* ck = CB + (size_t)k * DD;
        float E = emu_dot384_np(xr, ck);
        float s = __fadd_rn(__fsub_rn(xx, __fmul_rn(2.0f, E)), E2EMU[k]);
        if (s < best || (s == best && k < bidx)) { best = s; bidx = k; }
      }
#pragma unroll
      for (int m = 1; m < 64; m <<= 1) {
        float ob = __shfl_xor(best, m);
        int   oi = __shfl_xor(bidx, m);
        if (ob < best || (ob == best && oi < bidx)) { best = ob; bidx = oi; }
      }

      const int old = (int)IDXO[r];
      if (bidx != old) {
        const float* cn = CB + (size_t)bidx * DD;
        const float* co = CB + (size_t)old * DD;
        double dl = 0.0;
        for (int d = lane; d < DD; d += 64) {
          float xv = xr[d];
          float qn = cn[d], qo = co[d];
          Q[(size_t)r * DD + d] = qn;
          double en = (double)qn - (double)xv;
          double eo = (double)qo - (double)xv;
          dl += en * en - eo * eo;
        }
#pragma unroll
        for (int m = 1; m < 64; m <<= 1) dl += __shfl_xor(dl, m);
        if (lane == 0) {
          atomicAdd(DELTA + lvl, dl);
          IDXO[r] = (float)bidx;
        }
      }
    }
  }
}

// ---------------- loss finalize ----------------
__global__ void finalize_kernel(const double* __restrict__ p0, int n0, double w0,
                                const double* __restrict__ p1, int n1, double w1,
                                const double* __restrict__ p2, int n2, double w2,
                                const double* __restrict__ delta,
                                float* __restrict__ out) {
  __shared__ double red[4];
  int tid = threadIdx.x;
  double s0 = 0.0, s1 = 0.0, s2 = 0.0;
  for (int i = tid; i < n0; i += 256) s0 += p0[i];
  for (int i = tid; i < n1; i += 256) s1 += p1[i];
  for (int i = tid; i < n2; i += 256) s2 += p2[i];
  double v = s0 * w0 + s1 * w1 + s2 * w2;
#pragma unroll
  for (int m = 1; m < 64; m <<= 1) v += __shfl_xor(v, m);
  if ((tid & 63) == 0) red[tid >> 6] = v;
  __syncthreads();
  if (tid == 0)
    out[0] = (float)(red[0] + red[1] + red[2] + red[3]
                     + delta[0] * w0 + delta[1] * w1 + delta[2] * w2);
}

extern "C" void kernel_launch(void* const* d_in, const int* in_sizes, int n_in,
                              void* d_out, int out_size, void* d_ws, size_t ws_size,
                              hipStream_t stream) {
  const float* l0  = (const float*)d_in[0];
  const float* l1  = (const float*)d_in[1];
  const float* l2  = (const float*)d_in[2];
  const float* cb0 = (const float*)d_in[3];
  const float* cb1 = (const float*)d_in[4];
  const float* cb2 = (const float*)d_in[5];

  const size_t n_q0 = (size_t)in_sizes[0];
  const size_t n_q1 = (size_t)in_sizes[1];
  const size_t n_q2 = (size_t)in_sizes[2];
  const int r0 = (int)(n_q0 / DD);   // 65536
  const int r1 = (int)(n_q1 / DD);   // 262144
  const int r2 = (int)(n_q2 / DD);   // 262144

  float* out   = (float*)d_out;
  float* q0    = out;
  float* q1    = q0 + n_q0;
  float* q2    = q1 + n_q1;
  float* lossp = q2 + n_q2;
  float* idx0  = lossp + 1;
  float* idx1  = idx0 + r0;
  float* idx2  = idx1 + r1;

  // ws layout
  float*  e2    = (float*)d_ws;                          // 3*256 f32
  double* part  = (double*)((char*)d_ws + 4096);         // 9216 doubles
  double* delta = (double*)((char*)d_ws + 4096 + 73728);
  unsigned char* flag0 = (unsigned char*)d_ws + 4096 + 73728 + 1024;
  unsigned char* flag1 = flag0 + r0;
  unsigned char* flag2 = flag1 + r1;
  short* cbf0 = (short*)((char*)d_ws + (1 << 20));       // 3 x 384 KiB

  const int nb0 = r0 / TM, nb1 = r1 / TM, nb2 = r2 / TM;  // 1024/4096/4096
  double* p0 = part;
  double* p1 = p0 + nb0;
  double* p2 = p1 + nb1;

  prep_kernel<<<147, 256, 0, stream>>>(cb0, cb1, cb2, e2, delta, cbf0);

  vq_main<<<nb0 + nb1 + nb2, 256, 0, stream>>>(
      l0, l1, l2, cb0, cb1, cb2, cbf0, e2,
      q0, idx0, flag0, part, nb0, nb1);

  vq_refine<<<512, 256, 0, stream>>>(l0, l1, l2, cb0, cb1, cb2, e2,
                                     flag0, flag1, flag2, r0, r1, r2,
                                     q0, q1, q2, idx0, idx1, idx2, delta);

  const double w0 = 0.05 / ((double)r0 * DD);
  const double w1 = 0.25 / ((double)r1 * DD);
  const double w2 = 0.60 / ((double)r2 * DD);
  finalize_kernel<<<1, 256, 0, stream>>>(p0, nb0, w0, p1, nb1, w1, p2, nb2, w2,
                                         delta, lossp);
}